// Round 5
// baseline (63.578 us; speedup 1.0000x reference)
//
#include <hip/hip_runtime.h>
#include <hip/hip_cooperative_groups.h>

namespace cg = cooperative_groups;

#define D_  128
#define K2_ 256
#define BM  32

typedef short bf16x8 __attribute__((ext_vector_type(8)));
typedef float f32x4  __attribute__((ext_vector_type(4)));

__device__ __forceinline__ unsigned short f2bf(float f) {
  unsigned int u = __float_as_uint(f);
  u += 0x7fffu + ((u >> 16) & 1u);       // round-to-nearest-even
  return (unsigned short)(u >> 16);
}
__device__ __forceinline__ float bf2f(unsigned short s) {
  return __uint_as_float(((unsigned int)s) << 16);
}

// 8 consecutive f32 -> bf16x8 (hi only)
__device__ __forceinline__ bf16x8 cvt8(const float* p) {
  float4 a = *(const float4*)p, b = *(const float4*)(p + 4);
  bf16x8 r;
  r[0]=(short)f2bf(a.x); r[1]=(short)f2bf(a.y); r[2]=(short)f2bf(a.z); r[3]=(short)f2bf(a.w);
  r[4]=(short)f2bf(b.x); r[5]=(short)f2bf(b.y); r[6]=(short)f2bf(b.z); r[7]=(short)f2bf(b.w);
  return r;
}
// 8 consecutive f32 -> bf16 hi + bf16 lo residual
__device__ __forceinline__ void split8(const float* p, bf16x8* hi, bf16x8* lo) {
  float4 a = *(const float4*)p, b = *(const float4*)(p + 4);
  const float f[8] = {a.x, a.y, a.z, a.w, b.x, b.y, b.z, b.w};
  #pragma unroll
  for (int e = 0; e < 8; ++e) {
    unsigned short h = f2bf(f[e]);
    (*hi)[e] = (short)h;
    (*lo)[e] = (short)f2bf(f[e] - bf2f(h));
  }
}

// Packed-weight layout (validated in round 3):
//   elem addr = p*32768 + (c16*K32 + k32)*512 + lane*8 + e
//   lane = (c%16) | (((k%32)/8)<<4), e = k%8
// p0: B[k][c]=W1[c*128+k] hi (K32=4)   p1: same, lo residual
// p2: B[k][c]=W2[c*256+k] hi (K32=8)
// p3: B[k][c]=W2[k*256+c] hi (K32=4)
// p4: B[k][c]=W1[k*128+c] hi (K32=8)
__global__ __launch_bounds__(512, 2) void fused_jvp_kernel(
    const float* __restrict__ input_,
    const float* __restrict__ W1, const float* __restrict__ b1,
    const float* __restrict__ W2, const float* __restrict__ b2,
    unsigned short* __restrict__ wp,
    float* __restrict__ out)
{
  const int tid = threadIdx.x;

  // ---- pack phase: convert all weights once, chip-wide ----
  for (int idx = blockIdx.x * 512 + tid; idx < 163840; idx += 131072) {
    int p   = idx >> 15;
    int r   = idx & 32767;
    int e   = r & 7;
    int l   = (r >> 3) & 63;
    int blk = r >> 9;
    int sh  = (p == 2 || p == 4) ? 3 : 2;
    int k32 = blk & ((1 << sh) - 1);
    int c16 = blk >> sh;
    int c = c16 * 16 + (l & 15);
    int k = k32 * 32 + (l >> 4) * 8 + e;
    float v;
    if (p <= 1)      v = W1[c * 128 + k];
    else if (p == 2) v = W2[c * 256 + k];
    else if (p == 3) v = W2[k * 256 + c];
    else             v = W1[k * 128 + c];
    unsigned short h = f2bf(v);
    wp[idx] = (p == 1) ? f2bf(v - bf2f(h)) : h;
  }
  cg::this_grid().sync();

  // ---- compute phase: BM=32 rows/block, 8 waves ----
  __shared__ __align__(16) unsigned short hb [BM * K2_];   // 16 KB
  __shared__ __align__(16) unsigned short m2b[BM * K2_];   // 16 KB
  __shared__ __align__(16) unsigned short ub [BM * D_];    //  8 KB
  unsigned short* rbuf = m2b;   // alias: m2b dead after P2 K-loop, barrier between

  const unsigned short* p0 = wp;
  const unsigned short* p1 = wp + 32768;
  const unsigned short* p2 = wp + 65536;
  const unsigned short* p3 = wp + 98304;
  const unsigned short* p4 = wp + 131072;

  const int lane = tid & 63;
  const int wv   = tid >> 6;        // wave 0..7
  const int l15  = lane & 15;
  const int lg   = lane >> 4;       // 0..3
  const long rowbase = (long)blockIdx.x * BM;

  auto ldB = [&](const unsigned short* pk, int K32, int c16, int k32) -> bf16x8 {
    return *(const bf16x8*)(pk + (((c16 * K32 + k32) << 9) + (lane << 3)));
  };
  auto ldsA = [&](const unsigned short* tile, int S, int rb16, int kbase) -> bf16x8 {
    int row = rb16 + l15;
    int idx = (row * S + kbase + lg * 8) ^ ((row & 7) << 3);
    return *(const bf16x8*)(&tile[idx]);
  };

  const float* arow0 = input_ + (rowbase + l15) * 256;
  const float* arow1 = input_ + (rowbase + 16 + l15) * 256;

  // ---- P1: z1 = x*W1^T + b1 (3-term split) ; w = v*W1^T   (out 32x256)
  f32x4 accz[2][2] = {};
  f32x4 accw[2][2] = {};
  #pragma unroll
  for (int k32 = 0; k32 < 4; ++k32) {
    const int ko = k32 * 32 + lg * 8;
    bf16x8 axh0, axl0, axh1, axl1;
    split8(arow0 + ko, &axh0, &axl0);
    split8(arow1 + ko, &axh1, &axl1);
    bf16x8 av0 = cvt8(arow0 + 128 + ko);
    bf16x8 av1 = cvt8(arow1 + 128 + ko);
    #pragma unroll
    for (int nt = 0; nt < 2; ++nt) {
      const int c16 = wv * 2 + nt;
      bf16x8 bh = ldB(p0, 4, c16, k32);
      bf16x8 bl = ldB(p1, 4, c16, k32);
      accz[0][nt] = __builtin_amdgcn_mfma_f32_16x16x32_bf16(axh0, bh, accz[0][nt], 0, 0, 0);
      accz[0][nt] = __builtin_amdgcn_mfma_f32_16x16x32_bf16(axh0, bl, accz[0][nt], 0, 0, 0);
      accz[0][nt] = __builtin_amdgcn_mfma_f32_16x16x32_bf16(axl0, bh, accz[0][nt], 0, 0, 0);
      accw[0][nt] = __builtin_amdgcn_mfma_f32_16x16x32_bf16(av0,  bh, accw[0][nt], 0, 0, 0);
      accz[1][nt] = __builtin_amdgcn_mfma_f32_16x16x32_bf16(axh1, bh, accz[1][nt], 0, 0, 0);
      accz[1][nt] = __builtin_amdgcn_mfma_f32_16x16x32_bf16(axh1, bl, accz[1][nt], 0, 0, 0);
      accz[1][nt] = __builtin_amdgcn_mfma_f32_16x16x32_bf16(axl1, bh, accz[1][nt], 0, 0, 0);
      accw[1][nt] = __builtin_amdgcn_mfma_f32_16x16x32_bf16(av1,  bh, accw[1][nt], 0, 0, 0);
    }
  }
  unsigned int maskbits = 0;    // bit (mt*8 + nt*4 + q); reused in P3 (same lane map)
  #pragma unroll
  for (int mt = 0; mt < 2; ++mt)
  #pragma unroll
  for (int nt = 0; nt < 2; ++nt) {
    int cg = wv * 32 + nt * 16 + l15;
    float bias = b1[cg];
    #pragma unroll
    for (int q = 0; q < 4; ++q) {
      int rg = mt * 16 + lg * 4 + q;
      float z = accz[mt][nt][q] + bias;
      if (__builtin_expect(fabsf(z) < 1e-4f, 0)) {
        // borderline ReLU: recompute exactly in f64 (rare)
        const float* xr  = input_ + (rowbase + rg) * 256;
        const float* w1r = W1 + (size_t)cg * D_;
        double zd = (double)bias;
        for (int k = 0; k < D_; ++k) zd += (double)xr[k] * (double)w1r[k];
        z = (float)zd;
      }
      maskbits |= (z > 0.f ? 1u : 0u) << (mt * 8 + nt * 4 + q);
      float hv = z > 0.f ? z : 0.f;
      float mw = z > 0.f ? accw[mt][nt][q] : 0.f;
      int idx = (rg * K2_ + cg) ^ ((rg & 7) << 3);
      hb[idx]  = f2bf(hv);
      m2b[idx] = f2bf(mw);
    }
  }
  __syncthreads();

  // ---- P2: sdot = h*W2^T ; y = m2*W2^T  (out 32x128, wave owns 16 cols)
  f32x4 accs[2] = {};
  f32x4 accy[2] = {};
  #pragma unroll
  for (int k32 = 0; k32 < 8; ++k32) {
    bf16x8 bw = ldB(p2, 8, wv, k32);
    #pragma unroll
    for (int mt = 0; mt < 2; ++mt) {
      bf16x8 ah = ldsA(hb,  K2_, mt * 16, k32 * 32);
      bf16x8 am = ldsA(m2b, K2_, mt * 16, k32 * 32);
      accs[mt] = __builtin_amdgcn_mfma_f32_16x16x32_bf16(ah, bw, accs[mt], 0, 0, 0);
      accy[mt] = __builtin_amdgcn_mfma_f32_16x16x32_bf16(am, bw, accy[mt], 0, 0, 0);
    }
  }
  float coefr[2][4], ginvr[2][4], vreg[2][4];
  const int cg2 = wv * 16 + l15;
  {
    float bias = b2[cg2];
    float sgn  = (cg2 < 4) ? -1.f : 1.f;
    #pragma unroll
    for (int mt = 0; mt < 2; ++mt)
    #pragma unroll
    for (int q = 0; q < 4; ++q) {
      int rg = mt * 16 + lg * 4 + q;
      float sv = 1.f / (1.f + __expf(-(accs[mt][q] + bias)));
      float cf = sgn * sv * (1.f - sv);
      float gi = 1.f / ((sv + 0.618f) * sgn);
      coefr[mt][q] = cf;
      ginvr[mt][q] = gi;
      float vvf = input_[(rowbase + rg) * 256 + 128 + cg2];   // exact f32 v
      vreg[mt][q] = vvf;
      out[(rowbase + rg) * 256 + cg2] = vvf;                  // out[:, :128] = v
      int idxd = (rg * D_ + cg2) ^ ((rg & 7) << 3);
      ub[idxd] = f2bf(vvf * vvf * cf);                        // u = v^2 * coef
    }
  }
  __syncthreads();

  // ---- P3: p = u*W2  (out 32x256) ; r = mask .* p (mask from registers)
  f32x4 accp[2][2] = {};
  #pragma unroll
  for (int k32 = 0; k32 < 4; ++k32) {
    bf16x8 au0 = ldsA(ub, D_, 0,  k32 * 32);
    bf16x8 au1 = ldsA(ub, D_, 16, k32 * 32);
    #pragma unroll
    for (int nt = 0; nt < 2; ++nt) {
      bf16x8 bw = ldB(p3, 4, wv * 2 + nt, k32);
      accp[0][nt] = __builtin_amdgcn_mfma_f32_16x16x32_bf16(au0, bw, accp[0][nt], 0, 0, 0);
      accp[1][nt] = __builtin_amdgcn_mfma_f32_16x16x32_bf16(au1, bw, accp[1][nt], 0, 0, 0);
    }
  }
  #pragma unroll
  for (int mt = 0; mt < 2; ++mt)
  #pragma unroll
  for (int nt = 0; nt < 2; ++nt) {
    int cg = wv * 32 + nt * 16 + l15;
    #pragma unroll
    for (int q = 0; q < 4; ++q) {
      int rg = mt * 16 + lg * 4 + q;
      int idx = (rg * K2_ + cg) ^ ((rg & 7) << 3);
      rbuf[idx] = ((maskbits >> (mt * 8 + nt * 4 + q)) & 1u)
                ? f2bf(accp[mt][nt][q]) : (unsigned short)0;
    }
  }
  __syncthreads();

  // ---- P4: t1pre = r*W1  (out 32x128) ; final epilogue from registers
  f32x4 acct[2] = {};
  #pragma unroll
  for (int k32 = 0; k32 < 8; ++k32) {
    bf16x8 bw = ldB(p4, 8, wv, k32);
    #pragma unroll
    for (int mt = 0; mt < 2; ++mt) {
      bf16x8 ar = ldsA(rbuf, K2_, mt * 16, k32 * 32);
      acct[mt] = __builtin_amdgcn_mfma_f32_16x16x32_bf16(ar, bw, acct[mt], 0, 0, 0);
    }
  }
  #pragma unroll
  for (int mt = 0; mt < 2; ++mt)
  #pragma unroll
  for (int q = 0; q < 4; ++q) {
    int rg = mt * 16 + lg * 4 + q;
    float gi = ginvr[mt][q];
    float dv = -gi * acct[mt][q]
             + 2.f * vreg[mt][q] * gi * coefr[mt][q] * accy[mt][q];
    out[(rowbase + rg) * 256 + 128 + cg2] = dv;
  }
}

extern "C" void kernel_launch(void* const* d_in, const int* in_sizes, int n_in,
                              void* d_out, int out_size, void* d_ws, size_t ws_size,
                              hipStream_t stream) {
  const float* input_ = (const float*)d_in[1];
  const float* W1     = (const float*)d_in[2];
  const float* b1     = (const float*)d_in[3];
  const float* W2     = (const float*)d_in[4];
  const float* b2     = (const float*)d_in[5];
  float* out = (float*)d_out;
  unsigned short* wp = (unsigned short*)d_ws;
  int N = in_sizes[1] / (2 * D_);   // 8192 -> 256 blocks of BM=32

  void* args[] = {(void*)&input_, (void*)&W1, (void*)&b1, (void*)&W2,
                  (void*)&b2, (void*)&wp, (void*)&out};
  hipLaunchCooperativeKernel((void*)fused_jvp_kernel, dim3(N / BM), dim3(512),
                             args, 0, stream);
}

// Round 6
// 29.967 us; speedup vs baseline: 2.1216x; 2.1216x over previous
//
#include <hip/hip_runtime.h>

#define D_  128
#define K2_ 256
#define BM  32

typedef short bf16x8 __attribute__((ext_vector_type(8)));
typedef float f32x4  __attribute__((ext_vector_type(4)));

__device__ __forceinline__ unsigned short f2bf(float f) {
  unsigned int u = __float_as_uint(f);
  u += 0x7fffu + ((u >> 16) & 1u);       // round-to-nearest-even
  return (unsigned short)(u >> 16);
}
__device__ __forceinline__ float bf2f(unsigned short s) {
  return __uint_as_float(((unsigned int)s) << 16);
}

// 8 consecutive f32 -> bf16x8 (hi only)
__device__ __forceinline__ bf16x8 cvt8(const float* p) {
  float4 a = *(const float4*)p, b = *(const float4*)(p + 4);
  bf16x8 r;
  r[0]=(short)f2bf(a.x); r[1]=(short)f2bf(a.y); r[2]=(short)f2bf(a.z); r[3]=(short)f2bf(a.w);
  r[4]=(short)f2bf(b.x); r[5]=(short)f2bf(b.y); r[6]=(short)f2bf(b.z); r[7]=(short)f2bf(b.w);
  return r;
}
// 8 consecutive f32 -> bf16 hi + bf16 lo residual
__device__ __forceinline__ void split8(const float* p, bf16x8* hi, bf16x8* lo) {
  float4 a = *(const float4*)p, b = *(const float4*)(p + 4);
  const float f[8] = {a.x, a.y, a.z, a.w, b.x, b.y, b.z, b.w};
  #pragma unroll
  for (int e = 0; e < 8; ++e) {
    unsigned short h = f2bf(f[e]);
    (*hi)[e] = (short)h;
    (*lo)[e] = (short)f2bf(f[e] - bf2f(h));
  }
}

// ---------------- prep: pack weights into MFMA-fragment-ordered bf16 ----------------
//   elem addr = p*32768 + (c16*K32 + k32)*512 + lane*8 + e
//   lane = (c%16) | (((k%32)/8)<<4), e = k%8
// p0: B[k][c]=W1[c*128+k] hi (K32=4)   p1: same, lo residual
// p2: B[k][c]=W2[c*256+k] hi (K32=8)
// p3: B[k][c]=W2[k*256+c] hi (K32=4)
// p4: B[k][c]=W1[k*128+c] hi (K32=8)
__global__ __launch_bounds__(256) void prep_pack(
    const float* __restrict__ W1, const float* __restrict__ W2,
    unsigned short* __restrict__ ws)
{
  int idx = blockIdx.x * 256 + threadIdx.x;      // 640 blocks -> 163840 elems
  int p   = idx >> 15;
  int r   = idx & 32767;
  int e   = r & 7;
  int l   = (r >> 3) & 63;
  int blk = r >> 9;
  int sh  = (p == 2 || p == 4) ? 3 : 2;          // log2(K32)
  int k32 = blk & ((1 << sh) - 1);
  int c16 = blk >> sh;
  int c = c16 * 16 + (l & 15);
  int k = k32 * 32 + (l >> 4) * 8 + e;
  float v;
  if (p <= 1)      v = W1[c * 128 + k];
  else if (p == 2) v = W2[c * 256 + k];
  else if (p == 3) v = W2[k * 256 + c];
  else             v = W1[k * 128 + c];
  unsigned short h = f2bf(v);
  ws[idx] = (p == 1) ? f2bf(v - bf2f(h)) : h;
}

// ---------------- main fused kernel: BM=32 rows/block, 8 waves ----------------
__global__ __launch_bounds__(512, 2) void fused_jvp_kernel(
    const float* __restrict__ input_,
    const float* __restrict__ W1, const float* __restrict__ b1,
    const float* __restrict__ b2,
    const unsigned short* __restrict__ wp,
    float* __restrict__ out)
{
  __shared__ __align__(16) unsigned short hb [BM * K2_];   // 16 KB
  __shared__ __align__(16) unsigned short m2b[BM * K2_];   // 16 KB
  __shared__ __align__(16) unsigned short ub [BM * D_];    //  8 KB
  unsigned short* rbuf = m2b;   // alias: m2b dead after P2 K-loop, barrier between

  const unsigned short* p0 = wp;
  const unsigned short* p1 = wp + 32768;
  const unsigned short* p2 = wp + 65536;
  const unsigned short* p3 = wp + 98304;
  const unsigned short* p4 = wp + 131072;

  const int tid  = threadIdx.x;
  const int lane = tid & 63;
  const int wv   = tid >> 6;        // wave 0..7
  const int l15  = lane & 15;
  const int lg   = lane >> 4;       // 0..3
  const long rowbase = (long)blockIdx.x * BM;

  auto ldB = [&](const unsigned short* pk, int K32, int c16, int k32) -> bf16x8 {
    return *(const bf16x8*)(pk + (((c16 * K32 + k32) << 9) + (lane << 3)));
  };
  auto ldsA = [&](const unsigned short* tile, int S, int rb16, int kbase) -> bf16x8 {
    int row = rb16 + l15;
    int idx = (row * S + kbase + lg * 8) ^ ((row & 7) << 3);
    return *(const bf16x8*)(&tile[idx]);
  };

  const float* arow0 = input_ + (rowbase + l15) * 256;
  const float* arow1 = input_ + (rowbase + 16 + l15) * 256;

  // ---- P1: z1 = x*W1^T + b1 (3-term split) ; w = v*W1^T   (out 32x256)
  f32x4 accz[2][2] = {};
  f32x4 accw[2][2] = {};
  #pragma unroll
  for (int k32 = 0; k32 < 4; ++k32) {
    const int ko = k32 * 32 + lg * 8;
    bf16x8 axh0, axl0, axh1, axl1;
    split8(arow0 + ko, &axh0, &axl0);
    split8(arow1 + ko, &axh1, &axl1);
    bf16x8 av0 = cvt8(arow0 + 128 + ko);
    bf16x8 av1 = cvt8(arow1 + 128 + ko);
    #pragma unroll
    for (int nt = 0; nt < 2; ++nt) {
      const int c16 = wv * 2 + nt;
      bf16x8 bh = ldB(p0, 4, c16, k32);
      bf16x8 bl = ldB(p1, 4, c16, k32);
      accz[0][nt] = __builtin_amdgcn_mfma_f32_16x16x32_bf16(axh0, bh, accz[0][nt], 0, 0, 0);
      accz[0][nt] = __builtin_amdgcn_mfma_f32_16x16x32_bf16(axh0, bl, accz[0][nt], 0, 0, 0);
      accz[0][nt] = __builtin_amdgcn_mfma_f32_16x16x32_bf16(axl0, bh, accz[0][nt], 0, 0, 0);
      accw[0][nt] = __builtin_amdgcn_mfma_f32_16x16x32_bf16(av0,  bh, accw[0][nt], 0, 0, 0);
      accz[1][nt] = __builtin_amdgcn_mfma_f32_16x16x32_bf16(axh1, bh, accz[1][nt], 0, 0, 0);
      accz[1][nt] = __builtin_amdgcn_mfma_f32_16x16x32_bf16(axh1, bl, accz[1][nt], 0, 0, 0);
      accz[1][nt] = __builtin_amdgcn_mfma_f32_16x16x32_bf16(axl1, bh, accz[1][nt], 0, 0, 0);
      accw[1][nt] = __builtin_amdgcn_mfma_f32_16x16x32_bf16(av1,  bh, accw[1][nt], 0, 0, 0);
    }
  }
  unsigned int maskbits = 0;    // bit (mt*8 + nt*4 + q); reused in P3 (same lane map)
  #pragma unroll
  for (int mt = 0; mt < 2; ++mt)
  #pragma unroll
  for (int nt = 0; nt < 2; ++nt) {
    int cg = wv * 32 + nt * 16 + l15;
    float bias = b1[cg];
    #pragma unroll
    for (int q = 0; q < 4; ++q) {
      int rg = mt * 16 + lg * 4 + q;
      float z = accz[mt][nt][q] + bias;
      if (__builtin_expect(fabsf(z) < 1e-4f, 0)) {
        // borderline ReLU: recompute exactly in f64 (rare)
        const float* xr  = input_ + (rowbase + rg) * 256;
        const float* w1r = W1 + (size_t)cg * D_;
        double zd = (double)bias;
        for (int k = 0; k < D_; ++k) zd += (double)xr[k] * (double)w1r[k];
        z = (float)zd;
      }
      maskbits |= (z > 0.f ? 1u : 0u) << (mt * 8 + nt * 4 + q);
      float hv = z > 0.f ? z : 0.f;
      float mw = z > 0.f ? accw[mt][nt][q] : 0.f;
      int idx = (rg * K2_ + cg) ^ ((rg & 7) << 3);
      hb[idx]  = f2bf(hv);
      m2b[idx] = f2bf(mw);
    }
  }
  __syncthreads();

  // ---- P2: sdot = h*W2^T ; y = m2*W2^T  (out 32x128, wave owns 16 cols)
  f32x4 accs[2] = {};
  f32x4 accy[2] = {};
  #pragma unroll
  for (int k32 = 0; k32 < 8; ++k32) {
    bf16x8 bw = ldB(p2, 8, wv, k32);
    #pragma unroll
    for (int mt = 0; mt < 2; ++mt) {
      bf16x8 ah = ldsA(hb,  K2_, mt * 16, k32 * 32);
      bf16x8 am = ldsA(m2b, K2_, mt * 16, k32 * 32);
      accs[mt] = __builtin_amdgcn_mfma_f32_16x16x32_bf16(ah, bw, accs[mt], 0, 0, 0);
      accy[mt] = __builtin_amdgcn_mfma_f32_16x16x32_bf16(am, bw, accy[mt], 0, 0, 0);
    }
  }
  float coefr[2][4], ginvr[2][4], vreg[2][4];
  const int cg2 = wv * 16 + l15;
  {
    float bias = b2[cg2];
    float sgn  = (cg2 < 4) ? -1.f : 1.f;
    #pragma unroll
    for (int mt = 0; mt < 2; ++mt)
    #pragma unroll
    for (int q = 0; q < 4; ++q) {
      int rg = mt * 16 + lg * 4 + q;
      float sv = 1.f / (1.f + __expf(-(accs[mt][q] + bias)));
      float cf = sgn * sv * (1.f - sv);
      float gi = 1.f / ((sv + 0.618f) * sgn);
      coefr[mt][q] = cf;
      ginvr[mt][q] = gi;
      float vvf = input_[(rowbase + rg) * 256 + 128 + cg2];   // exact f32 v
      vreg[mt][q] = vvf;
      out[(rowbase + rg) * 256 + cg2] = vvf;                  // out[:, :128] = v
      int idxd = (rg * D_ + cg2) ^ ((rg & 7) << 3);
      ub[idxd] = f2bf(vvf * vvf * cf);                        // u = v^2 * coef
    }
  }
  __syncthreads();

  // ---- P3: p = u*W2  (out 32x256) ; r = mask .* p (mask from registers)
  f32x4 accp[2][2] = {};
  #pragma unroll
  for (int k32 = 0; k32 < 4; ++k32) {
    bf16x8 au0 = ldsA(ub, D_, 0,  k32 * 32);
    bf16x8 au1 = ldsA(ub, D_, 16, k32 * 32);
    #pragma unroll
    for (int nt = 0; nt < 2; ++nt) {
      bf16x8 bw = ldB(p3, 4, wv * 2 + nt, k32);
      accp[0][nt] = __builtin_amdgcn_mfma_f32_16x16x32_bf16(au0, bw, accp[0][nt], 0, 0, 0);
      accp[1][nt] = __builtin_amdgcn_mfma_f32_16x16x32_bf16(au1, bw, accp[1][nt], 0, 0, 0);
    }
  }
  #pragma unroll
  for (int mt = 0; mt < 2; ++mt)
  #pragma unroll
  for (int nt = 0; nt < 2; ++nt) {
    int cg = wv * 32 + nt * 16 + l15;
    #pragma unroll
    for (int q = 0; q < 4; ++q) {
      int rg = mt * 16 + lg * 4 + q;
      int idx = (rg * K2_ + cg) ^ ((rg & 7) << 3);
      rbuf[idx] = ((maskbits >> (mt * 8 + nt * 4 + q)) & 1u)
                ? f2bf(accp[mt][nt][q]) : (unsigned short)0;
    }
  }
  __syncthreads();

  // ---- P4: t1pre = r*W1  (out 32x128) ; final epilogue from registers
  f32x4 acct[2] = {};
  #pragma unroll
  for (int k32 = 0; k32 < 8; ++k32) {
    bf16x8 bw = ldB(p4, 8, wv, k32);
    #pragma unroll
    for (int mt = 0; mt < 2; ++mt) {
      bf16x8 ar = ldsA(rbuf, K2_, mt * 16, k32 * 32);
      acct[mt] = __builtin_amdgcn_mfma_f32_16x16x32_bf16(ar, bw, acct[mt], 0, 0, 0);
    }
  }
  #pragma unroll
  for (int mt = 0; mt < 2; ++mt)
  #pragma unroll
  for (int q = 0; q < 4; ++q) {
    int rg = mt * 16 + lg * 4 + q;
    float gi = ginvr[mt][q];
    float dv = -gi * acct[mt][q]
             + 2.f * vreg[mt][q] * gi * coefr[mt][q] * accy[mt][q];
    out[(rowbase + rg) * 256 + 128 + cg2] = dv;
  }
}

extern "C" void kernel_launch(void* const* d_in, const int* in_sizes, int n_in,
                              void* d_out, int out_size, void* d_ws, size_t ws_size,
                              hipStream_t stream) {
  const float* input_ = (const float*)d_in[1];
  const float* W1     = (const float*)d_in[2];
  const float* b1     = (const float*)d_in[3];
  const float* W2     = (const float*)d_in[4];
  const float* b2     = (const float*)d_in[5];
  float* out = (float*)d_out;
  unsigned short* wp = (unsigned short*)d_ws;
  int N = in_sizes[1] / (2 * D_);   // 8192 -> 256 blocks of BM=32

  prep_pack<<<dim3(640), dim3(256), 0, stream>>>(W1, W2, wp);
  fused_jvp_kernel<<<dim3(N / BM), dim3(512), 0, stream>>>(input_, W1, b1, b2, wp, out);
}

// Round 7
// 25.763 us; speedup vs baseline: 2.4679x; 1.1632x over previous
//
#include <hip/hip_runtime.h>

#define D_  128
#define K2_ 256
#define BM  32

typedef short bf16x8 __attribute__((ext_vector_type(8)));
typedef float f32x4  __attribute__((ext_vector_type(4)));

__device__ __forceinline__ unsigned short f2bf(float f) {
  unsigned int u = __float_as_uint(f);
  u += 0x7fffu + ((u >> 16) & 1u);       // round-to-nearest-even
  return (unsigned short)(u >> 16);
}
__device__ __forceinline__ float bf2f(unsigned short s) {
  return __uint_as_float(((unsigned int)s) << 16);
}

// ---------------- prep: pack weights into MFMA-fragment-ordered bf16 ----------------
//   elem addr = p*32768 + (c16*K32 + k32)*512 + lane*8 + e
//   lane = (c%16) | (((k%32)/8)<<4), e = k%8
// p0: B[k][c]=W1[c*128+k] hi (K32=4)   p1: same, lo residual
// p2: B[k][c]=W2[c*256+k] hi (K32=8)
// p3: B[k][c]=W2[k*256+c] hi (K32=4)
// p4: B[k][c]=W1[k*128+c] hi (K32=8)
__global__ __launch_bounds__(256) void prep_pack(
    const float* __restrict__ W1, const float* __restrict__ W2,
    unsigned short* __restrict__ ws)
{
  int idx = blockIdx.x * 256 + threadIdx.x;      // 640 blocks -> 163840 elems
  int p   = idx >> 15;
  int r   = idx & 32767;
  int e   = r & 7;
  int l   = (r >> 3) & 63;
  int blk = r >> 9;
  int sh  = (p == 2 || p == 4) ? 3 : 2;          // log2(K32)
  int k32 = blk & ((1 << sh) - 1);
  int c16 = blk >> sh;
  int c = c16 * 16 + (l & 15);
  int k = k32 * 32 + (l >> 4) * 8 + e;
  float v;
  if (p <= 1)      v = W1[c * 128 + k];
  else if (p == 2) v = W2[c * 256 + k];
  else if (p == 3) v = W2[k * 256 + c];
  else             v = W1[k * 128 + c];
  unsigned short h = f2bf(v);
  ws[idx] = (p == 1) ? f2bf(v - bf2f(h)) : h;
}

// ---------------- main fused kernel: BM=32 rows/block, 8 waves ----------------
__global__ __launch_bounds__(512, 2) void fused_jvp_kernel(
    const float* __restrict__ input_,
    const float* __restrict__ W1, const float* __restrict__ b1,
    const float* __restrict__ b2,
    const unsigned short* __restrict__ wp,
    float* __restrict__ out)
{
  __shared__ __align__(16) unsigned short xhi[BM * D_];    //  8 KB
  __shared__ __align__(16) unsigned short xlo[BM * D_];    //  8 KB
  __shared__ __align__(16) unsigned short vb [BM * D_];    //  8 KB
  __shared__ __align__(16) unsigned short hb [BM * K2_];   // 16 KB
  __shared__ __align__(16) unsigned short m2b[BM * K2_];   // 16 KB
  __shared__ __align__(16) unsigned short ub [BM * D_];    //  8 KB -> 64 KB total
  unsigned short* rbuf = m2b;   // alias: m2b dead after P2 K-loop, barrier between

  const unsigned short* p0 = wp;
  const unsigned short* p1 = wp + 32768;
  const unsigned short* p2 = wp + 65536;
  const unsigned short* p3 = wp + 98304;
  const unsigned short* p4 = wp + 131072;

  const int tid  = threadIdx.x;
  const int lane = tid & 63;
  const int wv   = tid >> 6;        // wave 0..7
  const int l15  = lane & 15;
  const int lg   = lane >> 4;       // 0..3
  const long rowbase = (long)blockIdx.x * BM;

  // ---- P0: stage x (hi+lo) and v as bf16 (swizzled); out[:, :128] = v coalesced
  #pragma unroll
  for (int it = 0; it < 4; ++it) {
    int flat4 = it * 512 + tid;          // float4 index in 32x256 tile
    int row   = flat4 >> 6;              // 64 float4 per row
    int col   = (flat4 & 63) * 4;
    const float4 val = *(const float4*)(input_ + (rowbase + row) * 256 + col);
    ushort4 hq;
    hq.x = f2bf(val.x); hq.y = f2bf(val.y); hq.z = f2bf(val.z); hq.w = f2bf(val.w);
    if (col < D_) {
      ushort4 lq;
      lq.x = f2bf(val.x - bf2f(hq.x));
      lq.y = f2bf(val.y - bf2f(hq.y));
      lq.z = f2bf(val.z - bf2f(hq.z));
      lq.w = f2bf(val.w - bf2f(hq.w));
      int idx = (row * D_ + col) ^ ((row & 7) << 3);
      *(ushort4*)(&xhi[idx]) = hq;
      *(ushort4*)(&xlo[idx]) = lq;
    } else {
      int c = col - D_;
      int idx = (row * D_ + c) ^ ((row & 7) << 3);
      *(ushort4*)(&vb[idx]) = hq;
      *(float4*)(out + (rowbase + row) * 256 + c) = val;   // out[:, :128] = v
    }
  }
  __syncthreads();

  auto ldB = [&](const unsigned short* pk, int K32, int c16, int k32) -> bf16x8 {
    return *(const bf16x8*)(pk + (((c16 * K32 + k32) << 9) + (lane << 3)));
  };
  auto ldsA = [&](const unsigned short* tile, int S, int rb16, int kbase) -> bf16x8 {
    int row = rb16 + l15;
    int idx = (row * S + kbase + lg * 8) ^ ((row & 7) << 3);
    return *(const bf16x8*)(&tile[idx]);
  };

  // ---- P1: z1 = x*W1^T + b1 (3-term split) ; w = v*W1^T   (out 32x256)
  f32x4 accz[2][2] = {};
  f32x4 accw[2][2] = {};
  #pragma unroll
  for (int k32 = 0; k32 < 4; ++k32) {
    bf16x8 axh0 = ldsA(xhi, D_, 0,  k32 * 32);
    bf16x8 axh1 = ldsA(xhi, D_, 16, k32 * 32);
    bf16x8 axl0 = ldsA(xlo, D_, 0,  k32 * 32);
    bf16x8 axl1 = ldsA(xlo, D_, 16, k32 * 32);
    bf16x8 av0  = ldsA(vb,  D_, 0,  k32 * 32);
    bf16x8 av1  = ldsA(vb,  D_, 16, k32 * 32);
    #pragma unroll
    for (int nt = 0; nt < 2; ++nt) {
      const int c16 = wv * 2 + nt;
      bf16x8 bh = ldB(p0, 4, c16, k32);
      bf16x8 bl = ldB(p1, 4, c16, k32);
      accz[0][nt] = __builtin_amdgcn_mfma_f32_16x16x32_bf16(axh0, bh, accz[0][nt], 0, 0, 0);
      accz[0][nt] = __builtin_amdgcn_mfma_f32_16x16x32_bf16(axh0, bl, accz[0][nt], 0, 0, 0);
      accz[0][nt] = __builtin_amdgcn_mfma_f32_16x16x32_bf16(axl0, bh, accz[0][nt], 0, 0, 0);
      accw[0][nt] = __builtin_amdgcn_mfma_f32_16x16x32_bf16(av0,  bh, accw[0][nt], 0, 0, 0);
      accz[1][nt] = __builtin_amdgcn_mfma_f32_16x16x32_bf16(axh1, bh, accz[1][nt], 0, 0, 0);
      accz[1][nt] = __builtin_amdgcn_mfma_f32_16x16x32_bf16(axh1, bl, accz[1][nt], 0, 0, 0);
      accz[1][nt] = __builtin_amdgcn_mfma_f32_16x16x32_bf16(axl1, bh, accz[1][nt], 0, 0, 0);
      accw[1][nt] = __builtin_amdgcn_mfma_f32_16x16x32_bf16(av1,  bh, accw[1][nt], 0, 0, 0);
    }
  }
  unsigned int maskbits = 0;    // bit (mt*8 + nt*4 + q); reused in P3 (same lane map)
  #pragma unroll
  for (int mt = 0; mt < 2; ++mt)
  #pragma unroll
  for (int nt = 0; nt < 2; ++nt) {
    int cg = wv * 32 + nt * 16 + l15;
    float bias = b1[cg];
    #pragma unroll
    for (int q = 0; q < 4; ++q) {
      int rg = mt * 16 + lg * 4 + q;
      float z = accz[mt][nt][q] + bias;
      if (__builtin_expect(fabsf(z) < 1e-4f, 0)) {
        // borderline ReLU: recompute exactly in f64 (rare)
        const float* xr  = input_ + (rowbase + rg) * 256;
        const float* w1r = W1 + (size_t)cg * D_;
        double zd = (double)bias;
        for (int k = 0; k < D_; ++k) zd += (double)xr[k] * (double)w1r[k];
        z = (float)zd;
      }
      maskbits |= (z > 0.f ? 1u : 0u) << (mt * 8 + nt * 4 + q);
      float hv = z > 0.f ? z : 0.f;
      float mw = z > 0.f ? accw[mt][nt][q] : 0.f;
      int idx = (rg * K2_ + cg) ^ ((rg & 7) << 3);
      hb[idx]  = f2bf(hv);
      m2b[idx] = f2bf(mw);
    }
  }
  __syncthreads();

  // ---- P2: sdot = h*W2^T ; y = m2*W2^T  (out 32x128, wave owns 16 cols)
  f32x4 accs[2] = {};
  f32x4 accy[2] = {};
  #pragma unroll
  for (int k32 = 0; k32 < 8; ++k32) {
    bf16x8 bw = ldB(p2, 8, wv, k32);
    #pragma unroll
    for (int mt = 0; mt < 2; ++mt) {
      bf16x8 ah = ldsA(hb,  K2_, mt * 16, k32 * 32);
      bf16x8 am = ldsA(m2b, K2_, mt * 16, k32 * 32);
      accs[mt] = __builtin_amdgcn_mfma_f32_16x16x32_bf16(ah, bw, accs[mt], 0, 0, 0);
      accy[mt] = __builtin_amdgcn_mfma_f32_16x16x32_bf16(am, bw, accy[mt], 0, 0, 0);
    }
  }
  float coefr[2][4], ginvr[2][4], vreg[2][4];
  const int cg2 = wv * 16 + l15;
  {
    float bias = b2[cg2];
    float sgn  = (cg2 < 4) ? -1.f : 1.f;
    #pragma unroll
    for (int mt = 0; mt < 2; ++mt)
    #pragma unroll
    for (int q = 0; q < 4; ++q) {
      int rg = mt * 16 + lg * 4 + q;
      float sv = 1.f / (1.f + __expf(-(accs[mt][q] + bias)));
      float cf = sgn * sv * (1.f - sv);
      float gi = 1.f / ((sv + 0.618f) * sgn);
      coefr[mt][q] = cf;
      ginvr[mt][q] = gi;
      float vvf = input_[(rowbase + rg) * 256 + 128 + cg2];   // exact f32 v
      vreg[mt][q] = vvf;
      int idxd = (rg * D_ + cg2) ^ ((rg & 7) << 3);
      ub[idxd] = f2bf(vvf * vvf * cf);                        // u = v^2 * coef
    }
  }
  __syncthreads();

  // ---- P3: p = u*W2  (out 32x256) ; r = mask .* p (mask from registers)
  f32x4 accp[2][2] = {};
  #pragma unroll
  for (int k32 = 0; k32 < 4; ++k32) {
    bf16x8 au0 = ldsA(ub, D_, 0,  k32 * 32);
    bf16x8 au1 = ldsA(ub, D_, 16, k32 * 32);
    #pragma unroll
    for (int nt = 0; nt < 2; ++nt) {
      bf16x8 bw = ldB(p3, 4, wv * 2 + nt, k32);
      accp[0][nt] = __builtin_amdgcn_mfma_f32_16x16x32_bf16(au0, bw, accp[0][nt], 0, 0, 0);
      accp[1][nt] = __builtin_amdgcn_mfma_f32_16x16x32_bf16(au1, bw, accp[1][nt], 0, 0, 0);
    }
  }
  #pragma unroll
  for (int mt = 0; mt < 2; ++mt)
  #pragma unroll
  for (int nt = 0; nt < 2; ++nt) {
    int cg = wv * 32 + nt * 16 + l15;
    #pragma unroll
    for (int q = 0; q < 4; ++q) {
      int rg = mt * 16 + lg * 4 + q;
      int idx = (rg * K2_ + cg) ^ ((rg & 7) << 3);
      rbuf[idx] = ((maskbits >> (mt * 8 + nt * 4 + q)) & 1u)
                ? f2bf(accp[mt][nt][q]) : (unsigned short)0;
    }
  }
  __syncthreads();

  // ---- P4: t1pre = r*W1  (out 32x128) ; final epilogue from registers
  f32x4 acct[2] = {};
  #pragma unroll
  for (int k32 = 0; k32 < 8; ++k32) {
    bf16x8 bw = ldB(p4, 8, wv, k32);
    #pragma unroll
    for (int mt = 0; mt < 2; ++mt) {
      bf16x8 ar = ldsA(rbuf, K2_, mt * 16, k32 * 32);
      acct[mt] = __builtin_amdgcn_mfma_f32_16x16x32_bf16(ar, bw, acct[mt], 0, 0, 0);
    }
  }
  #pragma unroll
  for (int mt = 0; mt < 2; ++mt)
  #pragma unroll
  for (int q = 0; q < 4; ++q) {
    int rg = mt * 16 + lg * 4 + q;
    float gi = ginvr[mt][q];
    float dv = -gi * acct[mt][q]
             + 2.f * vreg[mt][q] * gi * coefr[mt][q] * accy[mt][q];
    out[(rowbase + rg) * 256 + 128 + cg2] = dv;
  }
}

extern "C" void kernel_launch(void* const* d_in, const int* in_sizes, int n_in,
                              void* d_out, int out_size, void* d_ws, size_t ws_size,
                              hipStream_t stream) {
  const float* input_ = (const float*)d_in[1];
  const float* W1     = (const float*)d_in[2];
  const float* b1     = (const float*)d_in[3];
  const float* W2     = (const float*)d_in[4];
  const float* b2     = (const float*)d_in[5];
  float* out = (float*)d_out;
  unsigned short* wp = (unsigned short*)d_ws;
  int N = in_sizes[1] / (2 * D_);   // 8192 -> 256 blocks of BM=32

  prep_pack<<<dim3(640), dim3(256), 0, stream>>>(W1, W2, wp);
  fused_jvp_kernel<<<dim3(N / BM), dim3(512), 0, stream>>>(input_, W1, b1, b2, wp, out);
}